// Round 3
// baseline (383.463 us; speedup 1.0000x reference)
//
#include <hip/hip_runtime.h>

// Shapes (fixed by the problem)
//  x:      [32][256][56][56] f32     fc1_w: [65][256]   fc2_w: [4][65]  fc2_b: [4]
//  weight: [4][256][256][3][3] f32   bias:  [4][256]
//  out:    [32][256][56][56] f32
//
// ws layout (89,195,008 B total):
//  [0)        pooled [32][256] f32                    32768 B
//  [32768)    att    [32][4]  f32                       512 B
//  [33280)    aggb   [32][256] f32                    32768 B
//  [66048)    aggw   [32][256][9][256] bf16      37,748,736 B
//  [37814784) xb     [32][3136][256] bf16 (NHWC) 51,380,224 B

typedef short bf16x8 __attribute__((ext_vector_type(8)));
typedef float f32x16 __attribute__((ext_vector_type(16)));

__device__ __forceinline__ unsigned short f2bf(float f) {
  unsigned int u = __float_as_uint(f);
  unsigned int r = (u + 0x7FFFu + ((u >> 16) & 1u)) >> 16;  // RNE
  return (unsigned short)r;
}

// ---------------- K1: global average pool ----------------
__global__ void pool_k(const float* __restrict__ x, float* __restrict__ pooled) {
  int bc = blockIdx.x;             // b*256 + c
  int t = threadIdx.x;
  const float4* xp = (const float4*)(x + (size_t)bc * 3136);  // 784 float4
  float s = 0.f;
#pragma unroll
  for (int i = 0; i < 4; ++i) {
    int idx = t + i * 256;
    if (idx < 784) { float4 v = xp[idx]; s += (v.x + v.y) + (v.z + v.w); }
  }
#pragma unroll
  for (int off = 32; off > 0; off >>= 1) s += __shfl_down(s, off, 64);
  __shared__ float red[4];
  if ((t & 63) == 0) red[t >> 6] = s;
  __syncthreads();
  if (t == 0) pooled[bc] = (red[0] + red[1] + red[2] + red[3]) * (1.0f / 3136.0f);
}

// ---------------- K2: attention (fc1->relu->fc2->softmax) + agg_b ----------------
__global__ void att_k(const float* __restrict__ pooled, const float* __restrict__ fc1,
                      const float* __restrict__ fc2w, const float* __restrict__ fc2b,
                      const float* __restrict__ bias, float* __restrict__ att,
                      float* __restrict__ aggb) {
  int b = blockIdx.x, t = threadIdx.x;   // 64 threads
  __shared__ float p[256];
  __shared__ float h[65];
  __shared__ float a4[4];
  for (int i = t; i < 256; i += 64) p[i] = pooled[b * 256 + i];
  __syncthreads();
  for (int j = t; j < 65; j += 64) {
    float s = 0.f;
    for (int c = 0; c < 256; ++c) s += p[c] * fc1[j * 256 + c];
    h[j] = fmaxf(s, 0.f);
  }
  __syncthreads();
  if (t == 0) {
    float lg[4];
    for (int k = 0; k < 4; ++k) {
      float s = fc2b[k];
      for (int j = 0; j < 65; ++j) s += h[j] * fc2w[k * 65 + j];
      lg[k] = s * (1.0f / 34.0f);
    }
    float m = fmaxf(fmaxf(lg[0], lg[1]), fmaxf(lg[2], lg[3]));
    float e0 = expf(lg[0] - m), e1 = expf(lg[1] - m), e2 = expf(lg[2] - m), e3 = expf(lg[3] - m);
    float inv = 1.0f / (e0 + e1 + e2 + e3);
    a4[0] = e0 * inv; a4[1] = e1 * inv; a4[2] = e2 * inv; a4[3] = e3 * inv;
    for (int k = 0; k < 4; ++k) att[b * 4 + k] = a4[k];
  }
  __syncthreads();
  for (int o = t; o < 256; o += 64) {
    float s = 0.f;
    for (int k = 0; k < 4; ++k) s += a4[k] * bias[k * 256 + o];
    aggb[b * 256 + o] = s;
  }
}

// ---------------- K3: x NCHW f32 -> NHWC bf16 ----------------
__global__ void xcast_k(const float* __restrict__ x, unsigned short* __restrict__ xb) {
  __shared__ __align__(16) unsigned short tile[64 * 260];  // 64 hw x 256 c, pad 4
  int b = blockIdx.y;
  int hw0 = blockIdx.x * 64;   // 49 * 64 = 3136 exactly
  int t = threadIdx.x;
  int lane = t & 63, wq = t >> 6;   // wq in [0,4)
#pragma unroll 8
  for (int it = 0; it < 64; ++it) {
    int c = it * 4 + wq;
    float v = x[((size_t)(b * 256 + c)) * 3136 + hw0 + lane];
    tile[lane * 260 + c] = f2bf(v);
  }
  __syncthreads();
  int c4 = lane * 4;
#pragma unroll
  for (int it = 0; it < 16; ++it) {
    int hl = it * 4 + wq;
    ushort4 v = *(const ushort4*)&tile[hl * 260 + c4];
    *(ushort4*)&xb[((size_t)(b * 3136 + hw0 + hl)) * 256 + c4] = v;
  }
}

// ---------------- K4: agg_w[b][o][r][i] bf16 = sum_k att[b][k] * weight[k][o][i][r] ----------------
__global__ void aggw_k(const float* __restrict__ weight, const float* __restrict__ att,
                       unsigned short* __restrict__ aggw) {
  __shared__ float wl[4 * 2304];   // 4 banks x (256 i * 9 r), 36,864 B
  int o = blockIdx.x, t = threadIdx.x;   // 256 threads, thread t <-> i = t
  for (int k = 0; k < 4; ++k)
    for (int idx = t; idx < 2304; idx += 256)
      wl[k * 2304 + idx] = weight[((size_t)(k * 256 + o)) * 2304 + idx];
  __syncthreads();
  for (int b = 0; b < 32; ++b) {
    float a0 = att[b * 4 + 0], a1 = att[b * 4 + 1], a2 = att[b * 4 + 2], a3 = att[b * 4 + 3];
#pragma unroll
    for (int r = 0; r < 9; ++r) {
      float s = a0 * wl[t * 9 + r] + a1 * wl[2304 + t * 9 + r] +
                a2 * wl[4608 + t * 9 + r] + a3 * wl[6912 + t * 9 + r];
      aggw[(((size_t)b * 256 + o) * 9 + r) * 256 + t] = f2bf(s);
    }
  }
}

// ---------------- K5: per-sample conv as shifted MFMA-GEMM ----------------
// Block: 128 thr (2 waves). Tile: 64 o x 128 spatial. K-loop: 8 chunks of 32 ch.
// LDS: X [6 rows][64 cols][32 ch] bf16 @0 (24,576B) ; A [9 r][64 o][32 i] bf16 @24576 (36,864B)
#define LDS_A_OFF 24576

__global__ __launch_bounds__(128) void conv_k(const unsigned short* __restrict__ xb,
                                              const unsigned short* __restrict__ aggw,
                                              const float* __restrict__ aggb,
                                              float* __restrict__ out) {
  __shared__ __align__(16) unsigned char lds[61440];
  const int t = threadIdx.x;
  const int wid = t >> 6;        // wave 0/1 -> n-half
  const int lane = t & 63;
  const int l31 = lane & 31;
  const int q = lane >> 5;
  const int b = blockIdx.z;
  const int o0 = blockIdx.y * 64;
  const int n0 = blockIdx.x * 128;
  const int h0 = n0 / 56;

  // per-lane B-fragment geometry (n -> (row,col) in the staged tile)
  int bbase[2], nn[2];
#pragma unroll
  for (int nf = 0; nf < 2; ++nf) {
    int n = n0 + wid * 64 + nf * 32 + l31;
    int h = n / 56;
    int w = n - h * 56;
    nn[nf] = n;
    bbase[nf] = ((h - h0) * 64 + w) * 64 + q * 16;  // +dh*4096 +dw*64 +ks*32 at use
  }
  int abase[2];
#pragma unroll
  for (int mf = 0; mf < 2; ++mf)
    abase[mf] = LDS_A_OFF + (mf * 32 + l31) * 64 + q * 16;  // +r*4096 +ks*32 at use

  f32x16 acc[2][2];
#pragma unroll
  for (int i = 0; i < 2; ++i)
#pragma unroll
    for (int j = 0; j < 2; ++j)
#pragma unroll
      for (int e = 0; e < 16; ++e) acc[i][j][e] = 0.f;

  const size_t xbase_b = (size_t)b * 3136 * 256;
  const size_t abase_g = (size_t)(b * 256 + o0) * 2304;

  for (int ic = 0; ic < 8; ++ic) {
    __syncthreads();   // previous chunk's reads done before overwrite
    // ---- stage X: 1536 16B slots; slot -> pos=idx>>2 (row=pos>>6,col=pos&63), sub=idx&3
#pragma unroll
    for (int j = 0; j < 12; ++j) {
      int idx = j * 128 + t;
      int pos = idx >> 2, sub = idx & 3;
      int row = pos >> 6, col = pos & 63;
      int hg = h0 - 1 + row, wg = col - 1;
      uint4 v = make_uint4(0u, 0u, 0u, 0u);   // zero-pad halo / OOB
      if (col >= 1 && col <= 56 && hg >= 0 && hg < 56)
        v = *(const uint4*)(xb + xbase_b + (size_t)(hg * 56 + wg) * 256 + ic * 32 + sub * 8);
      *(uint4*)(lds + idx * 16) = v;
    }
    // ---- stage A: 2304 16B slots; pos -> r=pos>>6, ol=pos&63
#pragma unroll
    for (int j = 0; j < 18; ++j) {
      int idx = j * 128 + t;
      int pos = idx >> 2, sub = idx & 3;
      int r = pos >> 6, ol = pos & 63;
      uint4 v = *(const uint4*)(aggw + abase_g + (size_t)ol * 2304 + r * 256 + ic * 32 + sub * 8);
      *(uint4*)(lds + LDS_A_OFF + idx * 16) = v;
    }
    __syncthreads();
    // ---- compute: 9 taps x 2 k-steps x (2m x 2n) MFMAs
#pragma unroll
    for (int r = 0; r < 9; ++r) {
      const int dh = r / 3, dw = r % 3;
#pragma unroll
      for (int ks = 0; ks < 2; ++ks) {
        bf16x8 a0 = *(const bf16x8*)(lds + abase[0] + r * 4096 + ks * 32);
        bf16x8 a1 = *(const bf16x8*)(lds + abase[1] + r * 4096 + ks * 32);
        bf16x8 b0 = *(const bf16x8*)(lds + bbase[0] + dh * 4096 + dw * 64 + ks * 32);
        bf16x8 b1 = *(const bf16x8*)(lds + bbase[1] + dh * 4096 + dw * 64 + ks * 32);
        acc[0][0] = __builtin_amdgcn_mfma_f32_32x32x16_bf16(a0, b0, acc[0][0], 0, 0, 0);
        acc[0][1] = __builtin_amdgcn_mfma_f32_32x32x16_bf16(a0, b1, acc[0][1], 0, 0, 0);
        acc[1][0] = __builtin_amdgcn_mfma_f32_32x32x16_bf16(a1, b0, acc[1][0], 0, 0, 0);
        acc[1][1] = __builtin_amdgcn_mfma_f32_32x32x16_bf16(a1, b1, acc[1][1], 0, 0, 0);
      }
    }
  }

  // ---- epilogue: D layout col=lane&31 (n), row=(reg&3)+8*(reg>>2)+4*q (o)
#pragma unroll
  for (int mf = 0; mf < 2; ++mf) {
#pragma unroll
    for (int nf = 0; nf < 2; ++nf) {
      int n = nn[nf];
      if (n < 3136) {
#pragma unroll
        for (int reg = 0; reg < 16; ++reg) {
          int o = o0 + mf * 32 + (reg & 3) + 8 * (reg >> 2) + 4 * q;
          out[((size_t)(b * 256 + o)) * 3136 + n] = acc[mf][nf][reg] + aggb[b * 256 + o];
        }
      }
    }
  }
}

extern "C" void kernel_launch(void* const* d_in, const int* in_sizes, int n_in,
                              void* d_out, int out_size, void* d_ws, size_t ws_size,
                              hipStream_t stream) {
  const float* x      = (const float*)d_in[0];
  const float* fc1    = (const float*)d_in[1];
  const float* fc2w   = (const float*)d_in[2];
  const float* fc2b   = (const float*)d_in[3];
  const float* weight = (const float*)d_in[4];
  const float* bias   = (const float*)d_in[5];
  float* out = (float*)d_out;

  char* ws = (char*)d_ws;
  float* pooled         = (float*)(ws);
  float* att            = (float*)(ws + 32768);
  float* aggb           = (float*)(ws + 33280);
  unsigned short* aggw  = (unsigned short*)(ws + 66048);
  unsigned short* xb    = (unsigned short*)(ws + 66048 + 37748736);
  // total ws use: 89,195,008 B

  pool_k<<<32 * 256, 256, 0, stream>>>(x, pooled);
  att_k<<<32, 64, 0, stream>>>(pooled, fc1, fc2w, fc2b, bias, att, aggb);
  xcast_k<<<dim3(49, 32), 256, 0, stream>>>(x, xb);
  aggw_k<<<256, 256, 0, stream>>>(weight, att, aggw);
  conv_k<<<dim3(25, 4, 32), 128, 0, stream>>>(xb, aggw, aggb, out);
}

// Round 4
// 224.398 us; speedup vs baseline: 1.7088x; 1.7088x over previous
//
#include <hip/hip_runtime.h>

// Shapes: x [32][256][56][56] f32; fc1_w [65][256]; fc2_w [4][65]; fc2_b [4];
//         weight [4][256][256][3][3] f32; bias [4][256]; out [32][256][56][56] f32
//
// ws layout (89,195,008 B):
//  [0)        pooled [32][256] f32                         32768 B
//  [32768)    att    [32][4]  f32                            512 B
//  [33280)    aggb   [32][256] f32                         32768 B
//  [66048)    aggw   [32][4][16][9][64][16] bf16      37,748,736 B
//  [37814784) xb     [32][3136][256] bf16 (NHWC)      51,380,224 B

typedef short bf16x8 __attribute__((ext_vector_type(8)));
typedef float f32x16 __attribute__((ext_vector_type(16)));

__device__ __forceinline__ unsigned short f2bf(float f) {
  unsigned int u = __float_as_uint(f);
  return (unsigned short)((u + 0x7FFFu + ((u >> 16) & 1u)) >> 16);  // RNE
}
__device__ __forceinline__ float bf2f(unsigned short h) {
  return __uint_as_float(((unsigned int)h) << 16);
}

// ---------------- K1: x NCHW f32 -> NHWC bf16, fused global-avg-pool ----------------
__global__ void xcast_k(const float* __restrict__ x, unsigned short* __restrict__ xb,
                        float* __restrict__ pooled) {
  __shared__ __align__(16) unsigned short tile[64 * 260];  // 64 hw x 256 c (+4 pad)
  int b = blockIdx.y;
  int hw0 = blockIdx.x * 64;   // 49*64 = 3136
  int t = threadIdx.x;
  int lane = t & 63, wq = t >> 6;
#pragma unroll 8
  for (int it = 0; it < 64; ++it) {
    int c = it * 4 + wq;
    float v = x[((size_t)(b * 256 + c)) * 3136 + hw0 + lane];
    tile[lane * 260 + c] = f2bf(v);
  }
  __syncthreads();
  int c4 = lane * 4;
#pragma unroll
  for (int it = 0; it < 16; ++it) {
    int hl = it * 4 + wq;
    ushort4 v = *(const ushort4*)&tile[hl * 260 + c4];
    *(ushort4*)&xb[((size_t)(b * 3136 + hw0 + hl)) * 256 + c4] = v;
  }
  // fused pool: thread t <-> channel t; 2-B lane stride -> conflict-free
  float s = 0.f;
#pragma unroll 16
  for (int hl = 0; hl < 64; ++hl) s += bf2f(tile[hl * 260 + t]);
  atomicAdd(&pooled[b * 256 + t], s * (1.0f / 3136.0f));
}

// ---------------- K2: attention (fc1->relu->fc2->softmax/T) + agg_b ----------------
__global__ void att_k(const float* __restrict__ pooled, const float* __restrict__ fc1,
                      const float* __restrict__ fc2w, const float* __restrict__ fc2b,
                      const float* __restrict__ bias, float* __restrict__ att,
                      float* __restrict__ aggb) {
  int b = blockIdx.x, t = threadIdx.x;   // 64 threads
  __shared__ float p[256];
  __shared__ float h[65];
  __shared__ float a4[4];
  for (int i = t; i < 256; i += 64) p[i] = pooled[b * 256 + i];
  __syncthreads();
  for (int j = t; j < 65; j += 64) {
    float s = 0.f;
    for (int c = 0; c < 256; ++c) s += p[c] * fc1[j * 256 + c];
    h[j] = fmaxf(s, 0.f);
  }
  __syncthreads();
  if (t == 0) {
    float lg[4];
    for (int k = 0; k < 4; ++k) {
      float s = fc2b[k];
      for (int j = 0; j < 65; ++j) s += h[j] * fc2w[k * 65 + j];
      lg[k] = s * (1.0f / 34.0f);
    }
    float m = fmaxf(fmaxf(lg[0], lg[1]), fmaxf(lg[2], lg[3]));
    float e0 = expf(lg[0] - m), e1 = expf(lg[1] - m), e2 = expf(lg[2] - m), e3 = expf(lg[3] - m);
    float inv = 1.0f / (e0 + e1 + e2 + e3);
    a4[0] = e0 * inv; a4[1] = e1 * inv; a4[2] = e2 * inv; a4[3] = e3 * inv;
    for (int k = 0; k < 4; ++k) att[b * 4 + k] = a4[k];
  }
  __syncthreads();
  for (int o = t; o < 256; o += 64) {
    float s = 0.f;
    for (int k = 0; k < 4; ++k) s += a4[k] * bias[k * 256 + o];
    aggb[b * 256 + o] = s;
  }
}

// ---------------- K3: agg_w -> [b][ot][ic][r][ol 64][il 16] bf16 (conv staging order) --
__global__ void aggw_k(const float* __restrict__ weight, const float* __restrict__ att,
                       unsigned short* __restrict__ aggw) {
  __shared__ float wl[4 * 2304];
  int o = blockIdx.x, t = threadIdx.x;   // t = input channel i
  for (int k = 0; k < 4; ++k)
    for (int idx = t; idx < 2304; idx += 256)
      wl[k * 2304 + idx] = weight[((size_t)(k * 256 + o)) * 2304 + idx];
  __syncthreads();
  int ot = o >> 6, ol = o & 63, ic = t >> 4, il = t & 15;
  for (int b = 0; b < 32; ++b) {
    float a0 = att[b * 4 + 0], a1 = att[b * 4 + 1], a2 = att[b * 4 + 2], a3 = att[b * 4 + 3];
    size_t base = ((size_t)((b * 4 + ot) * 16 + ic)) * 9216 + ol * 16 + il;
#pragma unroll
    for (int r = 0; r < 9; ++r) {
      float s = a0 * wl[t * 9 + r] + a1 * wl[2304 + t * 9 + r] +
                a2 * wl[4608 + t * 9 + r] + a3 * wl[6912 + t * 9 + r];
      aggw[base + r * 1024] = f2bf(s);
    }
  }
}

// ---------------- K4: per-sample conv, shifted MFMA-GEMM, XOR-swizzled LDS ----------
// 256 thr (4 waves). Block tile 64o x 256n (wave = 64x64, 2x2 frags of 32x32x16).
// K-loop: 16 chunks of 16 ch. LDS: X [8 rows][64 cols][16ch] @0 (16,384B),
//                               A [9 r][64 o][16 i] @16384 (18,432B). Total 34,816B.
// Swizzle (both tiles, write+read): P = L ^ (((L>>5)&7)<<4)  [bits 4..6 ^= pos&7]
#define LDSA 16384

__global__ __launch_bounds__(256, 3) void conv_k(const unsigned short* __restrict__ xb,
                                                 const unsigned short* __restrict__ aggw,
                                                 const float* __restrict__ aggb,
                                                 float* __restrict__ out) {
  __shared__ __align__(16) unsigned char lds[16384 + 18432];
  const int t = threadIdx.x;
  const int wid = t >> 6;
  const int lane = t & 63;
  const int l31 = lane & 31;
  const int q = lane >> 5;

  // XCD-chunked bijective swizzle: 1664 blocks = 8 XCDs x 208
  int id = blockIdx.x;
  int wgid = (id & 7) * 208 + (id >> 3);
  int bn = wgid % 13;
  int rest = wgid / 13;
  int bo = rest & 3;
  int b = rest >> 2;

  const int o0 = bo * 64;
  const int n0 = bn * 256;
  const int h0 = n0 / 56;

  // B (X-tile) fragment geometry
  int bbase[2], nn[2], swz[2][3];
#pragma unroll
  for (int nf = 0; nf < 2; ++nf) {
    int n = n0 + wid * 64 + nf * 32 + l31;
    int h = n / 56, w = n - h * 56;
    nn[nf] = n;
    bbase[nf] = ((h - h0) * 64 + w) * 32 + q * 16;
#pragma unroll
    for (int dw = 0; dw < 3; ++dw) swz[nf][dw] = ((w + dw) & 7) << 4;
  }
  // A fragment geometry (swizzle is lane-constant: pos&7 = ol&7)
  int abase[2];
#pragma unroll
  for (int mf = 0; mf < 2; ++mf) {
    int ol = mf * 32 + l31;
    abase[mf] = (LDSA + ol * 32 + q * 16) ^ ((ol & 7) << 4);
  }

  // staging geometry, hoisted out of the K-loop
  int xsrc[4], xdst[4];   // X: 1024 slots of 16B
#pragma unroll
  for (int j = 0; j < 4; ++j) {
    int idx = j * 256 + t;
    int pos = idx >> 1, sub = idx & 1;
    int row = pos >> 6, col = pos & 63;
    int hg = h0 - 1 + row, wg2 = col - 1;
    bool valid = (col >= 1 && col <= 56 && hg >= 0 && hg < 56);
    xsrc[j] = valid ? ((hg * 56 + wg2) * 512 + sub * 16) : -1;   // bytes into image
    xdst[j] = (idx * 16) ^ ((pos & 7) << 4);
  }
  int adst[5];            // A: 1152 slots of 16B
#pragma unroll
  for (int j = 0; j < 5; ++j) {
    int idx = j * 256 + t;
    adst[j] = LDSA + ((idx * 16) ^ (((idx >> 1) & 7) << 4));
  }

  f32x16 acc[2][2];
#pragma unroll
  for (int i = 0; i < 2; ++i)
#pragma unroll
    for (int j = 0; j < 2; ++j)
#pragma unroll
      for (int e = 0; e < 16; ++e) acc[i][j][e] = 0.f;

  const char* xb_b = (const char*)xb + (size_t)b * 3136 * 512;
  const char* ag_c = (const char*)aggw + (size_t)(b * 4 + bo) * 16 * 18432;

  for (int ic = 0; ic < 16; ++ic) {
    __syncthreads();   // previous chunk's reads done before overwrite
    // ---- stage X (4 x uint4/thread), zero-filled halo
#pragma unroll
    for (int j = 0; j < 4; ++j) {
      uint4 v = make_uint4(0u, 0u, 0u, 0u);
      if (xsrc[j] >= 0) v = *(const uint4*)(xb_b + xsrc[j] + ic * 32);
      *(uint4*)(lds + xdst[j]) = v;
    }
    // ---- stage A: fully contiguous global reads (layout matches staging order)
#pragma unroll
    for (int j = 0; j < 5; ++j) {
      int idx = j * 256 + t;
      if (j < 4 || t < 128) {
        uint4 v = *(const uint4*)(ag_c + (size_t)ic * 18432 + idx * 16);
        *(uint4*)(lds + adst[j]) = v;
      }
    }
    __syncthreads();
    // ---- compute: 9 taps x (2m x 2n) MFMAs, k=16 per chunk
#pragma unroll
    for (int r = 0; r < 9; ++r) {
      const int dh = r / 3, dw = r % 3;
      bf16x8 a0 = *(const bf16x8*)(lds + abase[0] + r * 2048);
      bf16x8 a1 = *(const bf16x8*)(lds + abase[1] + r * 2048);
      bf16x8 b0 = *(const bf16x8*)(lds + ((bbase[0] + dh * 2048 + dw * 32) ^ swz[0][dw]));
      bf16x8 b1 = *(const bf16x8*)(lds + ((bbase[1] + dh * 2048 + dw * 32) ^ swz[1][dw]));
      acc[0][0] = __builtin_amdgcn_mfma_f32_32x32x16_bf16(a0, b0, acc[0][0], 0, 0, 0);
      acc[0][1] = __builtin_amdgcn_mfma_f32_32x32x16_bf16(a0, b1, acc[0][1], 0, 0, 0);
      acc[1][0] = __builtin_amdgcn_mfma_f32_32x32x16_bf16(a1, b0, acc[1][0], 0, 0, 0);
      acc[1][1] = __builtin_amdgcn_mfma_f32_32x32x16_bf16(a1, b1, acc[1][1], 0, 0, 0);
    }
  }

  // ---- epilogue: D layout col=lane&31 (n), row=(reg&3)+8*(reg>>2)+4*q (o)
#pragma unroll
  for (int mf = 0; mf < 2; ++mf) {
#pragma unroll
    for (int nf = 0; nf < 2; ++nf) {
      int n = nn[nf];
      if (n < 3136) {
#pragma unroll
        for (int reg = 0; reg < 16; ++reg) {
          int o = o0 + mf * 32 + (reg & 3) + 8 * (reg >> 2) + 4 * q;
          out[((size_t)(b * 256 + o)) * 3136 + n] = acc[mf][nf][reg] + aggb[b * 256 + o];
        }
      }
    }
  }
}

extern "C" void kernel_launch(void* const* d_in, const int* in_sizes, int n_in,
                              void* d_out, int out_size, void* d_ws, size_t ws_size,
                              hipStream_t stream) {
  const float* x      = (const float*)d_in[0];
  const float* fc1    = (const float*)d_in[1];
  const float* fc2w   = (const float*)d_in[2];
  const float* fc2b   = (const float*)d_in[3];
  const float* weight = (const float*)d_in[4];
  const float* bias   = (const float*)d_in[5];
  float* out = (float*)d_out;

  char* ws = (char*)d_ws;
  float* pooled         = (float*)(ws);
  float* att            = (float*)(ws + 32768);
  float* aggb           = (float*)(ws + 33280);
  unsigned short* aggw  = (unsigned short*)(ws + 66048);
  unsigned short* xb    = (unsigned short*)(ws + 66048 + 37748736);

  hipMemsetAsync(pooled, 0, 32768, stream);          // pooled accumulated via atomics
  xcast_k<<<dim3(49, 32), 256, 0, stream>>>(x, xb, pooled);
  att_k<<<32, 64, 0, stream>>>(pooled, fc1, fc2w, fc2b, bias, att, aggb);
  aggw_k<<<256, 256, 0, stream>>>(weight, att, aggw);
  conv_k<<<1664, 256, 0, stream>>>(xb, aggw, aggb, out);
}